// Round 5
// baseline (1792.695 us; speedup 1.0000x reference)
//
#include <hip/hip_runtime.h>

#define B_ 1024
#define T_ 366
#define NS_ 365
#define CD_ 24
#define NTASK (B_ * NS_)

__device__ __forceinline__ float sigm(float x) { return __fdividef(1.f, 1.f + __expf(-x)); }
__device__ __forceinline__ float rl(float v, int l) {
    return __int_as_float(__builtin_amdgcn_readlane(__float_as_int(v), l));
}

// ---- prologue: pack weights into 32-float aligned rows in d_ws ----
__global__ void mclstm_pack(const float* __restrict__ Wr, const float* __restrict__ br,
                            const float* __restrict__ Wp, const float* __restrict__ bp,
                            const float* __restrict__ Wc, const float* __restrict__ bc,
                            const float* __restrict__ Wa, const float* __restrict__ ba,
                            float* __restrict__ Wpk, float* __restrict__ Apk) {
    const int e = blockIdx.x * 64 + threadIdx.x;
    if (e < 576) {
#pragma unroll
        for (int k = 0; k < 24; ++k) Wpk[e * 32 + k] = Wr[e * 29 + k];
        Wpk[e * 32 + 24] = Wr[e * 29 + 25];   // rad coeff
        Wpk[e * 32 + 25] = br[e];             // bias
        Wpk[e * 32 + 26] = 0.f; Wpk[e * 32 + 27] = 0.f;
        Wpk[e * 32 + 28] = 0.f; Wpk[e * 32 + 29] = 0.f;
        Wpk[e * 32 + 30] = 0.f; Wpk[e * 32 + 31] = 0.f;
    } else if (e < 625) {
        const int r = e - 576;
#pragma unroll
        for (int k = 0; k < 29; ++k)
            Apk[r * 32 + k] = (r < 24) ? Wp[r * 29 + k] : (r < 48) ? Wc[(r - 24) * 29 + k] : Wa[k];
        Apk[r * 32 + 29] = (r < 24) ? bp[r] : (r < 48) ? bc[r - 24] : ba[0];
        Apk[r * 32 + 30] = 0.f; Apk[r * 32 + 31] = 0.f;
    }
}

// ---- main: 4 chains per block, 512 threads, weights from L1/L2, z in LDS ----
__global__ __launch_bounds__(512, 2) void mclstm_main(
    const float* __restrict__ X, const float* __restrict__ ORY,
    const float* __restrict__ Wpk, const float* __restrict__ Apk,
    float* __restrict__ Ccell, float* __restrict__ Cconv) {
    __shared__ float zb[8][680];     // [j*2+kind][r*28+c]; 680%32==8 -> bank-staggered
    __shared__ float cflat[96];      // C for 4 chains, [j*24+k]
    __shared__ float cmid[96];

    const int tid = threadIdx.x;
    const int w = tid >> 6, la = tid & 63;
    const int b0 = blockIdx.x * 4;

    const int e1 = tid, o1 = (e1 / 24) * 28 + e1 % 24;
    const bool two = (tid < 64);
    const int e2 = 512 + tid, o2 = (e2 / 24) * 28 + e2 % 24;
    const bool wa = (w >= 1 && w <= 4);          // aux waves (uniform)
    const int jc = wa ? (w - 1) : 0;             // aux chain
    const float* xj = X + (size_t)(b0 + jc) * T_ * 4;
    const float* oj = ORY + (size_t)(b0 + jc) * T_ * 7;
    const float4* w1p0 = (const float4*)(Wpk + (size_t)e1 * 32);
    const float4* w2p0 = (const float4*)(Wpk + (size_t)(two ? e2 : e1) * 32);
    const float4* aup0 = (const float4*)(Apk + (size_t)((la < 49) ? la : 48) * 32);

    if (tid < 96) cflat[tid] = 0.f;
    __syncthreads();

    float Ncum = 0.f;
    float rp0 = 0.f, rp1 = 0.f, rp2 = 0.f, rp3 = 0.f;

    for (int u = 0; u <= NS_; ++u) {
        const bool do1 = (u < NS_), doCv = (u > 0);

        // uniform per-chain rad for this step
        const int uu = do1 ? u : (NS_ - 1);  // safe addr at u==NS (value unused for kind0)
        const float ru0 = X[(size_t)(b0 + 0) * T_ * 4 + uu * 4];
        const float ru1 = X[(size_t)(b0 + 1) * T_ * 4 + uu * 4];
        const float ru2 = X[(size_t)(b0 + 2) * T_ * 4 + uu * 4];
        const float ru3 = X[(size_t)(b0 + 3) * T_ * 4 + uu * 4];

        // launder pointers: force in-loop L1 loads (no LICM/remat/spill games)
        const float4* w1p = w1p0; asm volatile("" : "+v"(w1p));
        const float4* w2p = w2p0; asm volatile("" : "+v"(w2p));
        const float4* aup = aup0; asm volatile("" : "+v"(aup));

        float w1[28], w2[28], au[32];
#pragma unroll
        for (int q = 0; q < 7; ++q) {
            const float4 v = w1p[q];
            w1[q * 4] = v.x; w1[q * 4 + 1] = v.y; w1[q * 4 + 2] = v.z; w1[q * 4 + 3] = v.w;
        }
        if (two) {
#pragma unroll
            for (int q = 0; q < 7; ++q) {
                const float4 v = w2p[q];
                w2[q * 4] = v.x; w2[q * 4 + 1] = v.y; w2[q * 4 + 2] = v.z; w2[q * 4 + 3] = v.w;
            }
        }
        if (wa) {
#pragma unroll
            for (int q = 0; q < 8; ++q) {
                const float4 v = aup[q];
                au[q * 4] = v.x; au[q * 4 + 1] = v.y; au[q * 4 + 2] = v.z; au[q * 4 + 3] = v.w;
            }
        }

        // lane-resident C for readlane broadcast
        const float vCa = cflat[la];
        const float vCb = cflat[64 + (la & 31)];

        float D10 = w1[25], D11 = w1[25], D12 = w1[25], D13 = w1[25];
        float D20 = 0.f, D21 = 0.f, D22 = 0.f, D23 = 0.f;
        if (two) { D20 = w2[25]; D21 = w2[25]; D22 = w2[25]; D23 = w2[25]; }
        float Da0 = 0.f, Da1 = 0.f, Da2 = 0.f, Da3 = 0.f;

#pragma unroll
        for (int k = 0; k < 24; ++k) {
            const float s0 = rl(vCa, k);
            const float s1 = rl(vCa, 24 + k);
            const float s2 = (k < 16) ? rl(vCa, 48 + k) : rl(vCb, k - 16);
            const float s3 = rl(vCb, 8 + k);
            D10 = fmaf(w1[k], s0, D10); D11 = fmaf(w1[k], s1, D11);
            D12 = fmaf(w1[k], s2, D12); D13 = fmaf(w1[k], s3, D13);
            if (two) {
                D20 = fmaf(w2[k], s0, D20); D21 = fmaf(w2[k], s1, D21);
                D22 = fmaf(w2[k], s2, D22); D23 = fmaf(w2[k], s3, D23);
            }
            if (wa) {
                Da0 = fmaf(au[k], s0, Da0); Da1 = fmaf(au[k], s1, Da1);
                Da2 = fmaf(au[k], s2, Da2); Da3 = fmaf(au[k], s3, Da3);
            }
        }

        // z writes (VMEM-free, small LDS traffic)
        const float w124 = w1[24];
        if (do1) {
            zb[0][o1] = fmaf(w124, ru0, D10); zb[2][o1] = fmaf(w124, ru1, D11);
            zb[4][o1] = fmaf(w124, ru2, D12); zb[6][o1] = fmaf(w124, ru3, D13);
        }
        if (doCv) {
            zb[1][o1] = fmaf(w124, rp0, D10); zb[3][o1] = fmaf(w124, rp1, D11);
            zb[5][o1] = fmaf(w124, rp2, D12); zb[7][o1] = fmaf(w124, rp3, D13);
        }
        if (two) {
            const float w224 = w2[24];
            if (do1) {
                zb[0][o2] = fmaf(w224, ru0, D20); zb[2][o2] = fmaf(w224, ru1, D21);
                zb[4][o2] = fmaf(w224, ru2, D22); zb[6][o2] = fmaf(w224, ru3, D23);
            }
            if (doCv) {
                zb[1][o2] = fmaf(w224, rp0, D20); zb[3][o2] = fmaf(w224, rp1, D21);
                zb[5][o2] = fmaf(w224, rp2, D22); zb[7][o2] = fmaf(w224, rp3, D23);
            }
        }

        // aux: part/cons/assim softmax fully in-wave -> cmid
        if (wa && do1) {
            const float radc = (jc == 0) ? ru0 : (jc == 1) ? ru1 : (jc == 2) ? ru2 : ru3;
            const float tmx = xj[u * 4 + 1], tmn = xj[u * 4 + 2];
            Ncum += xj[u * 4 + 3];
            const float dvs = oj[u * 7];
            const float tave = 0.5f * (tmx + tmn);
            const float cl = fminf(fmaxf(tave * 50.f, 10.f), 40.f);
            const float eff = 0.54f - (cl - 10.f) * (0.18f / 30.f);
            const float cpot = radc * (eff * (2.f * 0.5f / 3.6f * (12.f / 44.f)));

            const float da = (jc == 0) ? Da0 : (jc == 1) ? Da1 : (jc == 2) ? Da2 : Da3;
            float z = au[29] + da;
            z = fmaf(au[24], dvs, z);
            z = fmaf(au[25], radc, z);
            z = fmaf(au[26], tmx, z);
            z = fmaf(au[27], tmn, z);
            z = fmaf(au[28], Ncum, z);

            float pm = (la < 24) ? z : -1e30f;
#pragma unroll
            for (int o = 1; o < 32; o <<= 1) pm = fmaxf(pm, __shfl_xor(pm, o, 32));
            float pe = (la < 24) ? __expf(z - pm) : 0.f;
            float ps = pe;
#pragma unroll
            for (int o = 1; o < 32; o <<= 1) ps += __shfl_xor(ps, o, 32);
            const float conz = __shfl(z, 24 + (la & 31), 64);
            const float asmz = __shfl(z, 48, 64);
            if (la < 24) {
                const float part = __fdividef(pe, ps);
                const float cmv = cflat[jc * 24 + la];
                cmid[jc * 24 + la] = (cmv + sigm(asmz) * cpot * part) * (1.f - sigm(conz));
            }
        }
        __syncthreads();   // B1: zb + cmid ready

        // phase B: row softmax, mult folded (192 threads, b128)
        if (tid < 192) {
            const int j = tid / 48, kd = (tid / 24) & 1, r = tid % 24;
            if (kd == 0 ? do1 : doCv) {
                float* base = &zb[2 * j + kd][r * 28];
                float z[24];
#pragma unroll
                for (int q = 0; q < 6; ++q) {
                    const float4 v = ((const float4*)base)[q];
                    z[4 * q] = v.x; z[4 * q + 1] = v.y; z[4 * q + 2] = v.z; z[4 * q + 3] = v.w;
                }
                float m = z[0];
#pragma unroll
                for (int i = 1; i < 24; ++i) m = fmaxf(m, z[i]);
                float s = 0.f;
#pragma unroll
                for (int i = 0; i < 24; ++i) { z[i] = __expf(z[i] - m); s += z[i]; }
                const float mult = (kd == 0) ? cmid[j * 24 + r] : cflat[j * 24 + r];
                const float f = __fdividef(mult, s);
#pragma unroll
                for (int q = 0; q < 6; ++q) {
                    float4 v;
                    v.x = z[4 * q] * f; v.y = z[4 * q + 1] * f;
                    v.z = z[4 * q + 2] * f; v.w = z[4 * q + 3] * f;
                    ((float4*)base)[q] = v;
                }
            }
        }
        __syncthreads();   // B2: scaled P ready

        // phase C: column sums, c-major (bank-free)
        if (tid < 192) {
            const int j = tid & 3, kd = (tid >> 2) & 1, c = tid >> 3;
            if (kd == 0 ? do1 : doCv) {
                const float* base = &zb[2 * j + kd][0];
                float s = 0.f;
#pragma unroll
                for (int r = 0; r < 24; ++r) s += base[r * 28 + c];
                if (kd == 0) {
                    cflat[j * 24 + c] = s;
                    Ccell[((size_t)(b0 + j) * NS_ + u) * CD_ + c] = s;
                } else {
                    Cconv[((size_t)(b0 + j) * NS_ + (u - 1)) * CD_ + c] = s;
                }
            }
        }
        __syncthreads();   // B3: C(t+1) visible
        rp0 = ru0; rp1 = ru1; rp2 = ru2; rp3 = ru3;
    }
}

// ---- epilogue: all_day from Ccell (streaming) ----
__global__ __launch_bounds__(256) void mclstm_allday(
    const float* __restrict__ ORY, const float* __restrict__ c2a,
    const float* __restrict__ g2y, const float* __restrict__ Ccell,
    float* __restrict__ allday) {
    const int tid = blockIdx.x * 256 + threadIdx.x;
    if (tid < B_) {
#pragma unroll
        for (int k = 0; k < 7; ++k)
            allday[(size_t)tid * T_ * 7 + k] = ORY[(size_t)tid * T_ * 7 + k];
    }
    if (tid >= NTASK) return;
    const int b = tid / NS_;
    const int t = tid - b * NS_;

    const float* Cp = Ccell + (size_t)tid * CD_;
    float C[24];
#pragma unroll
    for (int q = 0; q < 6; ++q) {
        const float4 v = *(const float4*)(Cp + 4 * q);
        C[4 * q] = v.x; C[4 * q + 1] = v.y; C[4 * q + 2] = v.z; C[4 * q + 3] = v.w;
    }
    float pai = 0.f;
#pragma unroll
    for (int c = 0; c < 24; ++c) pai += fabsf(C[c] * c2a[c]);
    float lea = 0.f, ste = 0.f, gra = 0.f, yie = 0.f;
#pragma unroll
    for (int c = 0; c < 8; ++c) lea += C[c];
#pragma unroll
    for (int c = 8; c < 16; ++c) ste += C[c];
#pragma unroll
    for (int c = 16; c < 24; ++c) { gra += C[c]; yie += fabsf(C[c] * g2y[c - 16]); }
    lea /= 0.419f; ste /= 0.431f; gra /= 0.487f; yie /= 0.487f;
    const float agb = lea + ste + gra;

    float* ad = allday + ((size_t)b * T_ + (t + 1)) * 7;
    ad[0] = ORY[((size_t)b * T_ + (t + 1)) * 7];
    ad[1] = pai; ad[2] = lea; ad[3] = ste; ad[4] = gra; ad[5] = agb; ad[6] = yie;
}

extern "C" void kernel_launch(void* const* d_in, const int* in_sizes, int n_in,
                              void* d_out, int out_size, void* d_ws, size_t ws_size,
                              hipStream_t stream) {
    const float* X   = (const float*)d_in[0];
    const float* ORY = (const float*)d_in[1];
    const float* Wr  = (const float*)d_in[2];
    const float* br  = (const float*)d_in[3];
    const float* Wp  = (const float*)d_in[4];
    const float* bp  = (const float*)d_in[5];
    const float* Wc  = (const float*)d_in[6];
    const float* bc  = (const float*)d_in[7];
    const float* Wa  = (const float*)d_in[8];
    const float* ba  = (const float*)d_in[9];
    const float* c2a = (const float*)d_in[10];
    const float* g2y = (const float*)d_in[11];

    float* allday = (float*)d_out;
    float* Ccell  = allday + (size_t)B_ * T_ * 7;
    float* Cconv  = Ccell + (size_t)B_ * NS_ * CD_;

    float* Wpk = (float*)d_ws;            // 576*32 floats
    float* Apk = Wpk + 576 * 32;          // 49*32 floats

    hipLaunchKernelGGL(mclstm_pack, dim3(10), dim3(64), 0, stream,
                       Wr, br, Wp, bp, Wc, bc, Wa, ba, Wpk, Apk);
    hipLaunchKernelGGL(mclstm_main, dim3(B_ / 4), dim3(512), 0, stream,
                       X, ORY, Wpk, Apk, Ccell, Cconv);
    hipLaunchKernelGGL(mclstm_allday, dim3((NTASK + 255) / 256), dim3(256), 0, stream,
                       ORY, c2a, g2y, Ccell, allday);
}

// Round 6
// 1420.835 us; speedup vs baseline: 1.2617x; 1.2617x over previous
//
#include <hip/hip_runtime.h>

#define B_ 1024
#define T_ 366
#define NS_ 365
#define CD_ 24
#define NTASK (B_ * NS_)

__device__ __forceinline__ float sigm(float x) { return __fdividef(1.f, 1.f + __expf(-x)); }
__device__ __forceinline__ float rl(float v, int k) {
    return __int_as_float(__builtin_amdgcn_readlane(__float_as_int(v), k));
}

// ---- pack: Wpk[e*32 + {0..23 w, 24 rad, 25 bias}] ----
__global__ void mclstm_pack(const float* __restrict__ Wr, const float* __restrict__ br,
                            float* __restrict__ Wpk) {
    const int e = blockIdx.x * 64 + threadIdx.x;
    if (e < 576) {
#pragma unroll
        for (int k = 0; k < 24; ++k) Wpk[e * 32 + k] = Wr[e * 29 + k];
        Wpk[e * 32 + 24] = Wr[e * 29 + 25];
        Wpk[e * 32 + 25] = br[e];
#pragma unroll
        for (int k = 26; k < 32; ++k) Wpk[e * 32 + k] = 0.f;
    }
}

// ---- main: 4 chains/block, hybrid LDS+L1 weights, folded conv ----
__global__ __launch_bounds__(512, 1) void mclstm_main(
    const float* __restrict__ X, const float* __restrict__ ORY,
    const float* __restrict__ Wr, const float* __restrict__ br,
    const float* __restrict__ Wp, const float* __restrict__ bp,
    const float* __restrict__ Wc, const float* __restrict__ bc,
    const float* __restrict__ Wa, const float* __restrict__ ba,
    const float* __restrict__ Wpk,
    float* __restrict__ Ccell, float* __restrict__ Cconv)
{
    __shared__ float Wl[256 * 28];   // rows 0..255: w0..23, [24]=bias
    __shared__ float Ac[30 * 64];    // aux col-major: Ac[k*64+r]
    __shared__ float wrl[576];       // rad coeff, all rows
    __shared__ float Db[4][672];     // D; becomes kind1 scaled-P (col-major) after B1a
    __shared__ float Pb[4][672];     // kind0 scaled-P (col-major)
    __shared__ float cflat[96], cmidb[96];

    const int tid = threadIdx.x;
    const int b0 = blockIdx.x * 4;

    // ---- stage ----
    for (int i = tid; i < 256 * 28; i += 512) {
        const int e = i / 28, c = i - e * 28;
        Wl[i] = (c < 24) ? Wr[e * 29 + c] : (c == 24 ? br[e] : 0.f);
    }
    for (int i = tid; i < 30 * 64; i += 512) {
        const int k = i >> 6, r = i & 63;
        float v = 0.f;
        if (r < 49) {
            if (k < 29) v = (r < 24) ? Wp[r * 29 + k] : (r < 48) ? Wc[(r - 24) * 29 + k] : Wa[k];
            else        v = (r < 24) ? bp[r] : (r < 48) ? bc[r - 24] : ba[0];
        }
        Ac[i] = v;
    }
    for (int i = tid; i < 576; i += 512) wrl[i] = Wr[i * 29 + 25];
    if (tid < 96) cflat[tid] = 0.f;

    // roles
    const int e1 = tid;
    const int o1 = (e1 / 24) * 28 + e1 % 24;
    const bool two = (tid >= 448);
    const int e2 = tid + 64;                        // 512..575 for wave 7
    const int o2 = (e2 / 24) * 28 + e2 % 24;
    const int wv = tid >> 6, la = tid & 63;
    const bool auxw = (wv >= 1 && wv <= 4) && (la < 49);
    const int jc = auxw ? (wv - 1) : 0;
    const float* xj = X + (size_t)(b0 + jc) * T_ * 4;
    const float* oj = ORY + (size_t)(b0 + jc) * T_ * 7;

    // phase B decode (tid<384): 96 tasks (j,r) x 4 quarter-lanes
    const int bt = tid >> 2, qq = tid & 3;
    const int jB = bt / 24, rB = bt - jB * 24;
    // phase C decode (tid<384): 192 tasks (j,kind,c) x 2 halves
    const int ct = tid >> 1, hh = tid & 1;
    const int jC = ct / 48, remC = ct - jC * 48;
    const int kC = remC / 24, cC = remC - kC * 24;

    __syncthreads();

    float Ncum = 0.f;
    float rp0 = 0.f, rp1 = 0.f, rp2 = 0.f, rp3 = 0.f;

    for (int u = 0; u <= NS_; ++u) {
        const bool do1 = (u < NS_), doCv = (u > 0);
        const int uu = do1 ? u : (NS_ - 1);
        const float ru0 = X[(size_t)(b0 + 0) * T_ * 4 + uu * 4];
        const float ru1 = X[(size_t)(b0 + 1) * T_ * 4 + uu * 4];
        const float ru2 = X[(size_t)(b0 + 2) * T_ * 4 + uu * 4];
        const float ru3 = X[(size_t)(b0 + 3) * T_ * 4 + uu * 4];

        // ---- Phase A: shared dots ----
        const float vCa = cflat[la];
        const float vCb = cflat[64 + (la & 31)];

        float w1r[24], bias1;
        if (tid < 256) {
            const float4* wp = (const float4*)&Wl[e1 * 28];
#pragma unroll
            for (int q = 0; q < 6; ++q) {
                const float4 v = wp[q];
                w1r[4 * q] = v.x; w1r[4 * q + 1] = v.y; w1r[4 * q + 2] = v.z; w1r[4 * q + 3] = v.w;
            }
            bias1 = Wl[e1 * 28 + 24];
        } else {
            const float4* wp = (const float4*)&Wpk[(size_t)e1 * 32];
#pragma unroll
            for (int q = 0; q < 6; ++q) {
                const float4 v = wp[q];
                w1r[4 * q] = v.x; w1r[4 * q + 1] = v.y; w1r[4 * q + 2] = v.z; w1r[4 * q + 3] = v.w;
            }
            bias1 = wp[6].y;
        }
        float w2r[24], bias2 = 0.f;
        if (two) {
            const float4* wp = (const float4*)&Wpk[(size_t)e2 * 32];
#pragma unroll
            for (int q = 0; q < 6; ++q) {
                const float4 v = wp[q];
                w2r[4 * q] = v.x; w2r[4 * q + 1] = v.y; w2r[4 * q + 2] = v.z; w2r[4 * q + 3] = v.w;
            }
            bias2 = wp[6].y;
        }

        float D0 = bias1, D1 = bias1, D2 = bias1, D3 = bias1;
        float E0 = bias2, E1 = bias2, E2 = bias2, E3 = bias2;
#pragma unroll
        for (int k = 0; k < 24; ++k) {
            const float s0 = rl(vCa, k);
            const float s1 = rl(vCa, 24 + k);
            const float s2 = (k < 16) ? rl(vCa, 48 + k) : rl(vCb, k - 16);
            const float s3 = rl(vCb, 8 + k);
            D0 = fmaf(w1r[k], s0, D0); D1 = fmaf(w1r[k], s1, D1);
            D2 = fmaf(w1r[k], s2, D2); D3 = fmaf(w1r[k], s3, D3);
            if (two) {
                E0 = fmaf(w2r[k], s0, E0); E1 = fmaf(w2r[k], s1, E1);
                E2 = fmaf(w2r[k], s2, E2); E3 = fmaf(w2r[k], s3, E3);
            }
        }
        Db[0][o1] = D0; Db[1][o1] = D1; Db[2][o1] = D2; Db[3][o1] = D3;
        if (two) { Db[0][o2] = E0; Db[1][o2] = E1; Db[2][o2] = E2; Db[3][o2] = E3; }

        // ---- aux: part/cons/assim (in-wave) -> cmid ----
        if (auxw && do1) {
            const float radc = (jc == 0) ? ru0 : (jc == 1) ? ru1 : (jc == 2) ? ru2 : ru3;
            const float tmx = xj[u * 4 + 1], tmn = xj[u * 4 + 2];
            Ncum += xj[u * 4 + 3];
            const float dvs = oj[u * 7];
            const float tave = 0.5f * (tmx + tmn);
            const float cl = fminf(fmaxf(tave * 50.f, 10.f), 40.f);
            const float eff = 0.54f - (cl - 10.f) * (0.18f / 30.f);
            const float cpot = radc * (eff * (2.f * 0.5f / 3.6f * (12.f / 44.f)));

            float z = Ac[29 * 64 + la];
#pragma unroll
            for (int k = 0; k < 24; ++k) z = fmaf(Ac[k * 64 + la], cflat[jc * 24 + k], z);
            z = fmaf(Ac[24 * 64 + la], dvs, z);
            z = fmaf(Ac[25 * 64 + la], radc, z);
            z = fmaf(Ac[26 * 64 + la], tmx, z);
            z = fmaf(Ac[27 * 64 + la], tmn, z);
            z = fmaf(Ac[28 * 64 + la], Ncum, z);

            float pm = (la < 24) ? z : -1e30f;
#pragma unroll
            for (int o = 1; o < 32; o <<= 1) pm = fmaxf(pm, __shfl_xor(pm, o, 32));
            float pe = (la < 24) ? __expf(z - pm) : 0.f;
            float ps = pe;
#pragma unroll
            for (int o = 1; o < 32; o <<= 1) ps += __shfl_xor(ps, o, 32);
            const float conz = __shfl(z, 24 + (la & 31), 64);
            const float asmz = __shfl(z, 48, 64);
            if (la < 24) {
                const float part = __fdividef(pe, ps);
                cmidb[jc * 24 + la] =
                    (cflat[jc * 24 + la] + sigm(asmz) * cpot * part) * (1.f - sigm(conz));
            }
        }
        __syncthreads();   // B1: Db(D), cmid ready

        // ---- Phase B read/compute: z0/z1, softmax (4 lanes per row) ----
        float sc0[6], sc1[6];
        if (tid < 384) {
            const float ruJ = (jB == 0) ? ru0 : (jB == 1) ? ru1 : (jB == 2) ? ru2 : ru3;
            const float rpJ = (jB == 0) ? rp0 : (jB == 1) ? rp1 : (jB == 2) ? rp2 : rp3;
            float dd[6], wr6[6];
#pragma unroll
            for (int i = 0; i < 6; ++i) {
                dd[i]  = Db[jB][rB * 28 + 6 * qq + i];
                wr6[i] = wrl[rB * 24 + 6 * qq + i];
            }
            float z0[6], z1[6];
            float m0 = -1e30f, m1 = -1e30f;
#pragma unroll
            for (int i = 0; i < 6; ++i) {
                z0[i] = fmaf(wr6[i], ruJ, dd[i]);
                z1[i] = fmaf(wr6[i], rpJ, dd[i]);
                m0 = fmaxf(m0, z0[i]); m1 = fmaxf(m1, z1[i]);
            }
            m0 = fmaxf(m0, __shfl_xor(m0, 1)); m0 = fmaxf(m0, __shfl_xor(m0, 2));
            m1 = fmaxf(m1, __shfl_xor(m1, 1)); m1 = fmaxf(m1, __shfl_xor(m1, 2));
            float s0 = 0.f, s1 = 0.f;
#pragma unroll
            for (int i = 0; i < 6; ++i) {
                z0[i] = __expf(z0[i] - m0); s0 += z0[i];
                z1[i] = __expf(z1[i] - m1); s1 += z1[i];
            }
            s0 += __shfl_xor(s0, 1); s0 += __shfl_xor(s0, 2);
            s1 += __shfl_xor(s1, 1); s1 += __shfl_xor(s1, 2);
            const float f0 = __fdividef(cmidb[jB * 24 + rB], s0);
            const float f1 = __fdividef(cflat[jB * 24 + rB], s1);
#pragma unroll
            for (int i = 0; i < 6; ++i) { sc0[i] = z0[i] * f0; sc1[i] = z1[i] * f1; }
        }
        __syncthreads();   // B1a: all D reads complete

        if (tid < 384) {
            if (do1) {
#pragma unroll
                for (int i = 0; i < 6; ++i) Pb[jB][(6 * qq + i) * 28 + rB] = sc0[i];
            }
            if (doCv) {
#pragma unroll
                for (int i = 0; i < 6; ++i) Db[jB][(6 * qq + i) * 28 + rB] = sc1[i];
            }
        }
        __syncthreads();   // B2: scaled P (col-major) ready

        // ---- Phase C: column sums (2 lanes per column) ----
        if (tid < 384 && (kC ? doCv : do1)) {
            const float* src = kC ? &Db[jC][0] : &Pb[jC][0];
            const float4* p4 = (const float4*)&src[cC * 28 + 12 * hh];
            float s = 0.f;
#pragma unroll
            for (int i = 0; i < 3; ++i) {
                const float4 v = p4[i];
                s += (v.x + v.y) + (v.z + v.w);
            }
            s += __shfl_xor(s, 1);
            if (hh == 0) {
                if (kC == 0) {
                    cflat[jC * 24 + cC] = s;
                    Ccell[((size_t)(b0 + jC) * NS_ + u) * CD_ + cC] = s;
                } else {
                    Cconv[((size_t)(b0 + jC) * NS_ + (u - 1)) * CD_ + cC] = s;
                }
            }
        }
        __syncthreads();   // B3: C(t+1) visible
        rp0 = ru0; rp1 = ru1; rp2 = ru2; rp3 = ru3;
    }
}

// ---- epilogue: all_day (streaming) ----
__global__ __launch_bounds__(256) void mclstm_allday(
    const float* __restrict__ ORY, const float* __restrict__ c2a,
    const float* __restrict__ g2y, const float* __restrict__ Ccell,
    float* __restrict__ allday) {
    const int tid = blockIdx.x * 256 + threadIdx.x;
    if (tid < B_) {
#pragma unroll
        for (int k = 0; k < 7; ++k)
            allday[(size_t)tid * T_ * 7 + k] = ORY[(size_t)tid * T_ * 7 + k];
    }
    if (tid >= NTASK) return;
    const int b = tid / NS_;
    const int t = tid - b * NS_;

    const float* Cp = Ccell + (size_t)tid * CD_;
    float C[24];
#pragma unroll
    for (int q = 0; q < 6; ++q) {
        const float4 v = *(const float4*)(Cp + 4 * q);
        C[4 * q] = v.x; C[4 * q + 1] = v.y; C[4 * q + 2] = v.z; C[4 * q + 3] = v.w;
    }
    float pai = 0.f;
#pragma unroll
    for (int c = 0; c < 24; ++c) pai += fabsf(C[c] * c2a[c]);
    float lea = 0.f, ste = 0.f, gra = 0.f, yie = 0.f;
#pragma unroll
    for (int c = 0; c < 8; ++c) lea += C[c];
#pragma unroll
    for (int c = 8; c < 16; ++c) ste += C[c];
#pragma unroll
    for (int c = 16; c < 24; ++c) { gra += C[c]; yie += fabsf(C[c] * g2y[c - 16]); }
    lea /= 0.419f; ste /= 0.431f; gra /= 0.487f; yie /= 0.487f;
    const float agb = lea + ste + gra;

    float* ad = allday + ((size_t)b * T_ + (t + 1)) * 7;
    ad[0] = ORY[((size_t)b * T_ + (t + 1)) * 7];
    ad[1] = pai; ad[2] = lea; ad[3] = ste; ad[4] = gra; ad[5] = agb; ad[6] = yie;
}

extern "C" void kernel_launch(void* const* d_in, const int* in_sizes, int n_in,
                              void* d_out, int out_size, void* d_ws, size_t ws_size,
                              hipStream_t stream) {
    const float* X   = (const float*)d_in[0];
    const float* ORY = (const float*)d_in[1];
    const float* Wr  = (const float*)d_in[2];
    const float* br  = (const float*)d_in[3];
    const float* Wp  = (const float*)d_in[4];
    const float* bp  = (const float*)d_in[5];
    const float* Wc  = (const float*)d_in[6];
    const float* bc  = (const float*)d_in[7];
    const float* Wa  = (const float*)d_in[8];
    const float* ba  = (const float*)d_in[9];
    const float* c2a = (const float*)d_in[10];
    const float* g2y = (const float*)d_in[11];

    float* allday = (float*)d_out;
    float* Ccell  = allday + (size_t)B_ * T_ * 7;
    float* Cconv  = Ccell + (size_t)B_ * NS_ * CD_;

    float* Wpk = (float*)d_ws;   // 576*32 floats

    hipLaunchKernelGGL(mclstm_pack, dim3(9), dim3(64), 0, stream, Wr, br, Wpk);
    hipLaunchKernelGGL(mclstm_main, dim3(B_ / 4), dim3(512), 0, stream,
                       X, ORY, Wr, br, Wp, bp, Wc, bc, Wa, ba, Wpk, Ccell, Cconv);
    hipLaunchKernelGGL(mclstm_allday, dim3((NTASK + 255) / 256), dim3(256), 0, stream,
                       ORY, c2a, g2y, Ccell, allday);
}

// Round 7
// 867.546 us; speedup vs baseline: 2.0664x; 1.6378x over previous
//
#include <hip/hip_runtime.h>

#define B_ 1024
#define T_ 366
#define NS_ 365
#define CD_ 24

__device__ __forceinline__ float sigm(float x) { return __fdividef(1.f, 1.f + __expf(-x)); }
__device__ __forceinline__ float rl(float v, int k) {
    return __int_as_float(__builtin_amdgcn_readlane(__float_as_int(v), k));
}

// ---- pack: Wpk[e][32] = {w0..23, rad, bias}; Apk[r][32] = {w0..28, bias} ----
__global__ void mclstm_pack(const float* __restrict__ Wr, const float* __restrict__ br,
                            const float* __restrict__ Wp, const float* __restrict__ bp,
                            const float* __restrict__ Wc, const float* __restrict__ bc,
                            const float* __restrict__ Wa, const float* __restrict__ ba,
                            float* __restrict__ Wpk, float* __restrict__ Apk) {
    const int e = blockIdx.x * 64 + threadIdx.x;
    if (e < 576) {
#pragma unroll
        for (int k = 0; k < 24; ++k) Wpk[e * 32 + k] = Wr[e * 29 + k];
        Wpk[e * 32 + 24] = Wr[e * 29 + 25];
        Wpk[e * 32 + 25] = br[e];
#pragma unroll
        for (int k = 26; k < 32; ++k) Wpk[e * 32 + k] = 0.f;
    } else if (e < 625) {
        const int r = e - 576;
#pragma unroll
        for (int k = 0; k < 29; ++k)
            Apk[r * 32 + k] = (r < 24) ? Wp[r * 29 + k] : (r < 48) ? Wc[(r - 24) * 29 + k] : Wa[k];
        Apk[r * 32 + 29] = (r < 24) ? bp[r] : (r < 48) ? bc[r - 24] : ba[0];
        Apk[r * 32 + 30] = 0.f; Apk[r * 32 + 31] = 0.f;
    }
}

// ---- main: one wave per chain; weights VGPR-resident (waves_per_eu(1,1)) ----
__global__ __attribute__((amdgpu_flat_work_group_size(64, 64), amdgpu_waves_per_eu(1, 1)))
void mclstm_main(const float* __restrict__ X, const float* __restrict__ ORY,
                 const float* __restrict__ Wpk, const float* __restrict__ Apk,
                 const float* __restrict__ c2a, const float* __restrict__ g2y,
                 float* __restrict__ allday, float* __restrict__ Ccell,
                 float* __restrict__ Cconv)
{
    __shared__ float zb1[600];   // stride 25 (coprime 32): conflict-free rows & cols
    __shared__ float zb2[600];

    const int l = threadIdx.x;
    const int b = blockIdx.x;

    // 9 redis rows per lane: e = l + 64j
    float wrg[9][24], wrad[9], brg[9];
    int za[9];
#pragma unroll
    for (int j = 0; j < 9; ++j) {
        const int e = l + 64 * j;
        const float4* wp = (const float4*)(Wpk + (size_t)e * 32);
#pragma unroll
        for (int q = 0; q < 6; ++q) {
            const float4 v = wp[q];
            wrg[j][4*q] = v.x; wrg[j][4*q+1] = v.y; wrg[j][4*q+2] = v.z; wrg[j][4*q+3] = v.w;
        }
        const float4 t = wp[6];
        wrad[j] = t.x; brg[j] = t.y;
        za[j] = (e / 24) * 25 + (e % 24);
    }
    // one aux row per lane (part 0..23, cons 24..47, assim 48)
    float wx[29], bx;
    {
        const int r = (l < 49) ? l : 48;
        const float4* ap = (const float4*)(Apk + (size_t)r * 32);
        float tmp[32];
#pragma unroll
        for (int q = 0; q < 8; ++q) {
            const float4 v = ap[q];
            tmp[4*q] = v.x; tmp[4*q+1] = v.y; tmp[4*q+2] = v.z; tmp[4*q+3] = v.w;
        }
#pragma unroll
        for (int k = 0; k < 29; ++k) wx[k] = tmp[k];
        bx = tmp[29];
    }
    const float c2 = (l < 24) ? c2a[l] : 0.f;
    const float gy = (l >= 16 && l < 24) ? g2y[l - 16] : 0.f;

    const float* xrow = X + (size_t)b * T_ * 4;
    const float* orow = ORY + (size_t)b * T_ * 7;

    if (l < 7) allday[(size_t)b * T_ * 7 + l] = orow[l];  // all_day row 0

    float vC = 0.f, Ncum = 0.f, radp = 0.f;

    for (int u = 0; u <= NS_; ++u) {
        const bool do1 = (u < NS_), doCv = (u > 0);
        const int uu = do1 ? u : (NS_ - 1);
        const float rad = xrow[uu * 4 + 0];
        const float tmx = xrow[uu * 4 + 1];
        const float tmn = xrow[uu * 4 + 2];
        const float x3  = xrow[uu * 4 + 3];
        const float dvs = orow[uu * 7];

        if (do1) Ncum += x3;

        // broadcast C (SGPRs via readlane)
        float Cs[24];
#pragma unroll
        for (int k = 0; k < 24; ++k) Cs[k] = rl(vC, k);

        const float tave = 0.5f * (tmx + tmn);
        const float clm = fminf(fmaxf(tave * 50.f, 10.f), 40.f);
        const float eff = 0.54f - (clm - 10.f) * (0.18f / 30.f);
        const float cpot = rad * (eff * (2.f * 0.5f / 3.6f * (12.f / 44.f)));

        // shared dots: D = bias + W·C ; z1 = D + wrad*rad(u) ; z2 = D + wrad*rad(u-1)
#pragma unroll
        for (int j = 0; j < 9; ++j) {
            float p0 = brg[j], p1 = 0.f, p2 = 0.f, p3 = 0.f;
#pragma unroll
            for (int k = 0; k < 24; k += 4) {
                p0 = fmaf(wrg[j][k],   Cs[k],   p0);
                p1 = fmaf(wrg[j][k+1], Cs[k+1], p1);
                p2 = fmaf(wrg[j][k+2], Cs[k+2], p2);
                p3 = fmaf(wrg[j][k+3], Cs[k+3], p3);
            }
            const float D = (p0 + p1) + (p2 + p3);
            zb1[za[j]] = fmaf(wrad[j], rad, D);
            if (doCv) zb2[za[j]] = fmaf(wrad[j], radp, D);
        }

        // aux row + in-wave part/cons/assim -> cmid (valid on lanes 0..23)
        float cmid;
        {
            float z = bx;
#pragma unroll
            for (int k = 0; k < 24; ++k) z = fmaf(wx[k], Cs[k], z);
            z = fmaf(wx[24], dvs, z);
            z = fmaf(wx[25], rad, z);
            z = fmaf(wx[26], tmx, z);
            z = fmaf(wx[27], tmn, z);
            z = fmaf(wx[28], Ncum, z);
            float pm = (l < 24) ? z : -1e30f;
#pragma unroll
            for (int o = 1; o < 32; o <<= 1) pm = fmaxf(pm, __shfl_xor(pm, o, 32));
            float pe = (l < 24) ? __expf(z - pm) : 0.f;
            float ps = pe;
#pragma unroll
            for (int o = 1; o < 32; o <<= 1) ps += __shfl_xor(ps, o, 32);
            const float conz = __shfl(z, 24 + (l & 31), 64);
            const float asmz = __shfl(z, 48, 64);
            const float part = __fdividef(pe, ps);
            cmid = (vC + sigm(asmz) * cpot * part) * (1.f - sigm(conz));
        }
        __syncthreads();   // zb1/zb2 visible

        // row softmax: lanes 0..23 kind0 (mult=cmid), lanes 24..47 kind1 (mult=C_prev[r])
        {
            const int r = (l < 24) ? l : (l - 24);
            const float mlt_s = __shfl(vC, r, 64);
            const float mlt = (l < 24) ? cmid : mlt_s;
            const bool act = (l < 24) ? do1 : ((l < 48) && doCv);
            float* zbp = (l < 24) ? zb1 : zb2;
            if (act) {
                float z[24];
#pragma unroll
                for (int c = 0; c < 24; ++c) z[c] = zbp[r * 25 + c];
                float m0 = z[0], m1 = z[1], m2 = z[2], m3 = z[3];
#pragma unroll
                for (int c = 4; c < 24; c += 4) {
                    m0 = fmaxf(m0, z[c]);   m1 = fmaxf(m1, z[c+1]);
                    m2 = fmaxf(m2, z[c+2]); m3 = fmaxf(m3, z[c+3]);
                }
                const float m = fmaxf(fmaxf(m0, m1), fmaxf(m2, m3));
                float s0 = 0.f, s1 = 0.f, s2 = 0.f, s3 = 0.f;
#pragma unroll
                for (int c = 0; c < 24; c += 4) {
                    z[c]   = __expf(z[c]   - m); s0 += z[c];
                    z[c+1] = __expf(z[c+1] - m); s1 += z[c+1];
                    z[c+2] = __expf(z[c+2] - m); s2 += z[c+2];
                    z[c+3] = __expf(z[c+3] - m); s3 += z[c+3];
                }
                const float f = __fdividef(mlt, (s0 + s1) + (s2 + s3));
#pragma unroll
                for (int c = 0; c < 24; ++c) zbp[r * 25 + c] = z[c] * f;
            }
        }
        __syncthreads();   // scaled P ready

        // colsum + outputs + folded all_day
        {
            const int c = (l < 24) ? l : (l - 24);
            const bool a0 = (l < 24) && do1;
            const bool a1 = (l >= 24 && l < 48) && doCv;
            const float* zbp = (l < 24) ? zb1 : zb2;
            float s = 0.f;
            if (a0 || a1) {
                float t0 = 0.f, t1 = 0.f, t2 = 0.f, t3 = 0.f;
#pragma unroll
                for (int r = 0; r < 24; r += 4) {
                    t0 += zbp[r*25 + c];     t1 += zbp[(r+1)*25 + c];
                    t2 += zbp[(r+2)*25 + c]; t3 += zbp[(r+3)*25 + c];
                }
                s = (t0 + t1) + (t2 + t3);
            }
            if (a1) Cconv[((size_t)b * NS_ + (u - 1)) * CD_ + c] = s;
            if (a0) {
                vC = s;
                Ccell[((size_t)b * NS_ + u) * CD_ + c] = s;
            }
            if (do1) {
                const float cv = (l < 24) ? vC : 0.f;
                const float pv = fabsf(cv * c2);
                const float yv = fabsf(cv * gy);
                float a8 = cv, p8 = pv, y8 = yv;
#pragma unroll
                for (int o = 1; o < 8; o <<= 1) {
                    a8 += __shfl_xor(a8, o, 8);
                    p8 += __shfl_xor(p8, o, 8);
                    y8 += __shfl_xor(y8, o, 8);
                }
                const float pai = rl(p8, 0) + rl(p8, 8) + rl(p8, 16);
                const float lea = rl(a8, 0)  * (1.f / 0.419f);
                const float ste = rl(a8, 8)  * (1.f / 0.431f);
                const float gra = rl(a8, 16) * (1.f / 0.487f);
                const float yie = rl(y8, 16) * (1.f / 0.487f);
                const float agb = lea + ste + gra;
                const float dvsn = orow[(u + 1) * 7];
                if (l < 7) {
                    float val = dvsn;
                    val = (l == 1) ? pai : val;
                    val = (l == 2) ? lea : val;
                    val = (l == 3) ? ste : val;
                    val = (l == 4) ? gra : val;
                    val = (l == 5) ? agb : val;
                    val = (l == 6) ? yie : val;
                    allday[((size_t)b * T_ + (u + 1)) * 7 + l] = val;
                }
            }
        }
        __syncthreads();
        radp = rad;
    }
}

extern "C" void kernel_launch(void* const* d_in, const int* in_sizes, int n_in,
                              void* d_out, int out_size, void* d_ws, size_t ws_size,
                              hipStream_t stream) {
    const float* X   = (const float*)d_in[0];
    const float* ORY = (const float*)d_in[1];
    const float* Wr  = (const float*)d_in[2];
    const float* br  = (const float*)d_in[3];
    const float* Wp  = (const float*)d_in[4];
    const float* bp  = (const float*)d_in[5];
    const float* Wc  = (const float*)d_in[6];
    const float* bc  = (const float*)d_in[7];
    const float* Wa  = (const float*)d_in[8];
    const float* ba  = (const float*)d_in[9];
    const float* c2a = (const float*)d_in[10];
    const float* g2y = (const float*)d_in[11];

    float* allday = (float*)d_out;
    float* Ccell  = allday + (size_t)B_ * T_ * 7;
    float* Cconv  = Ccell + (size_t)B_ * NS_ * CD_;

    float* Wpk = (float*)d_ws;            // 576*32 floats
    float* Apk = Wpk + 576 * 32;          // 49*32 floats

    hipLaunchKernelGGL(mclstm_pack, dim3(10), dim3(64), 0, stream,
                       Wr, br, Wp, bp, Wc, bc, Wa, ba, Wpk, Apk);
    hipLaunchKernelGGL(mclstm_main, dim3(B_), dim3(64), 0, stream,
                       X, ORY, Wpk, Apk, c2a, g2y, allday, Ccell, Cconv);
}

// Round 8
// 788.260 us; speedup vs baseline: 2.2742x; 1.1006x over previous
//
#include <hip/hip_runtime.h>

#define B_ 1024
#define T_ 366
#define NS_ 365
#define CD_ 24

__device__ __forceinline__ float sigm(float x) { return __fdividef(1.f, 1.f + __expf(-x)); }
__device__ __forceinline__ float rl(float v, int k) {
    return __int_as_float(__builtin_amdgcn_readlane(__float_as_int(v), k));
}

// ---- pack: Wpk[e][32] = {w0..23, rad, bias}; Apk[r][32] = {w0..28, bias} ----
__global__ void mclstm_pack(const float* __restrict__ Wr, const float* __restrict__ br,
                            const float* __restrict__ Wp, const float* __restrict__ bp,
                            const float* __restrict__ Wc, const float* __restrict__ bc,
                            const float* __restrict__ Wa, const float* __restrict__ ba,
                            float* __restrict__ Wpk, float* __restrict__ Apk) {
    const int e = blockIdx.x * 64 + threadIdx.x;
    if (e < 576) {
#pragma unroll
        for (int k = 0; k < 24; ++k) Wpk[e * 32 + k] = Wr[e * 29 + k];
        Wpk[e * 32 + 24] = Wr[e * 29 + 25];
        Wpk[e * 32 + 25] = br[e];
#pragma unroll
        for (int k = 26; k < 32; ++k) Wpk[e * 32 + k] = 0.f;
    } else if (e < 625) {
        const int r = e - 576;
#pragma unroll
        for (int k = 0; k < 29; ++k)
            Apk[r * 32 + k] = (r < 24) ? Wp[r * 29 + k] : (r < 48) ? Wc[(r - 24) * 29 + k] : Wa[k];
        Apk[r * 32 + 29] = (r < 24) ? bp[r] : (r < 48) ? bc[r - 24] : ba[0];
        Apk[r * 32 + 30] = 0.f; Apk[r * 32 + 31] = 0.f;
    }
}

// ---- main: one chain per 128-thread block (2 waves); weights VGPR-resident ----
__global__ __attribute__((amdgpu_flat_work_group_size(128, 128), amdgpu_waves_per_eu(2, 2)))
void mclstm_main(const float* __restrict__ X, const float* __restrict__ ORY,
                 const float* __restrict__ Wpk, const float* __restrict__ Apk,
                 const float* __restrict__ c2a, const float* __restrict__ g2y,
                 float* __restrict__ allday, float* __restrict__ Ccell,
                 float* __restrict__ Cconv)
{
    __shared__ float zb1[600], zb2[600];                   // row-major z, stride 25
    __shared__ alignas(16) float pb1[672], pb2[672];       // col-major scaled P, stride 28
    __shared__ alignas(16) float cbuf[24];
    __shared__ float cmb[24];

    const int tid = threadIdx.x;
    const int l = tid & 63;          // lane within wave
    const int wv = tid >> 6;         // wave 0/1
    const int b = blockIdx.x;

    // 4 register-resident redis rows: e = tid + 128j
    float wrg[4][24], wrad[4], brg[4];
    int za[4];
#pragma unroll
    for (int j = 0; j < 4; ++j) {
        const int e = tid + 128 * j;
        const float4* wp = (const float4*)(Wpk + (size_t)e * 32);
#pragma unroll
        for (int q = 0; q < 6; ++q) {
            const float4 v = wp[q];
            wrg[j][4*q] = v.x; wrg[j][4*q+1] = v.y; wrg[j][4*q+2] = v.z; wrg[j][4*q+3] = v.w;
        }
        const float4 t = wp[6];
        wrad[j] = t.x; brg[j] = t.y;
        za[j] = (e / 24) * 25 + (e % 24);
    }
    // union extra row: wave0 = redis row 512+l; wave1 = aux row min(l,48)
    float ext[32];
    {
        const float4* p = (const float4*)((wv == 0) ? (Wpk + (size_t)(512 + l) * 32)
                                                    : (Apk + (size_t)((l < 49) ? l : 48) * 32));
#pragma unroll
        for (int q = 0; q < 8; ++q) {
            const float4 v = p[q];
            ext[4*q] = v.x; ext[4*q+1] = v.y; ext[4*q+2] = v.z; ext[4*q+3] = v.w;
        }
    }
    const int za4 = ((512 + l) / 24) * 25 + ((512 + l) % 24);

    // all_day per-lane constants (C_new[c] lives in lane 2c)
    const bool even = ((l & 1) == 0) && (l < 48);
    const float c2 = even ? c2a[l >> 1] : 0.f;
    const float gy = (even && l >= 32) ? g2y[(l >> 1) - 16] : 0.f;

    const float* xrow = X + (size_t)b * T_ * 4;
    const float* orow = ORY + (size_t)b * T_ * 7;

    if (tid < 7) allday[(size_t)b * T_ * 7 + tid] = orow[tid];
    if (tid < 24) cbuf[tid] = 0.f;
    __syncthreads();

    float Ncum = 0.f, radp = 0.f;

    for (int u = 0; u <= NS_; ++u) {
        const bool do1 = (u < NS_), doCv = (u > 0);
        const int uu = do1 ? u : (NS_ - 1);
        const float rad = xrow[uu * 4 + 0];

        // broadcast C (LDS b128, same addr across lanes)
        float Cs[24];
#pragma unroll
        for (int q = 0; q < 6; ++q) {
            const float4 v = ((const float4*)cbuf)[q];
            Cs[4*q] = v.x; Cs[4*q+1] = v.y; Cs[4*q+2] = v.z; Cs[4*q+3] = v.w;
        }

        // ---- Phase A: shared dots; z1 = D + wrad*rad_u, z2 = D + wrad*rad_{u-1} ----
#pragma unroll
        for (int j = 0; j < 4; ++j) {
            float p0 = brg[j], p1 = 0.f, p2 = 0.f, p3 = 0.f;
#pragma unroll
            for (int k = 0; k < 24; k += 4) {
                p0 = fmaf(wrg[j][k],   Cs[k],   p0);
                p1 = fmaf(wrg[j][k+1], Cs[k+1], p1);
                p2 = fmaf(wrg[j][k+2], Cs[k+2], p2);
                p3 = fmaf(wrg[j][k+3], Cs[k+3], p3);
            }
            const float D = (p0 + p1) + (p2 + p3);
            if (do1)  zb1[za[j]] = fmaf(wrad[j], rad,  D);
            if (doCv) zb2[za[j]] = fmaf(wrad[j], radp, D);
        }

        if (wv == 0) {
            // 5th redis row (bias at ext[25], rad coeff at ext[24])
            float p0 = ext[25], p1 = 0.f, p2 = 0.f, p3 = 0.f;
#pragma unroll
            for (int k = 0; k < 24; k += 4) {
                p0 = fmaf(ext[k],   Cs[k],   p0);
                p1 = fmaf(ext[k+1], Cs[k+1], p1);
                p2 = fmaf(ext[k+2], Cs[k+2], p2);
                p3 = fmaf(ext[k+3], Cs[k+3], p3);
            }
            const float D = (p0 + p1) + (p2 + p3);
            if (do1)  zb1[za4] = fmaf(ext[24], rad,  D);
            if (doCv) zb2[za4] = fmaf(ext[24], radp, D);
        } else if (do1) {
            // aux row + in-wave part/cons/assim -> cmid
            const float tmx = xrow[uu * 4 + 1], tmn = xrow[uu * 4 + 2];
            Ncum += xrow[uu * 4 + 3];
            const float dvs = orow[uu * 7];
            const float tave = 0.5f * (tmx + tmn);
            const float clm = fminf(fmaxf(tave * 50.f, 10.f), 40.f);
            const float eff = 0.54f - (clm - 10.f) * (0.18f / 30.f);
            const float cpot = rad * (eff * (2.f * 0.5f / 3.6f * (12.f / 44.f)));

            float z = ext[29];
#pragma unroll
            for (int k = 0; k < 24; ++k) z = fmaf(ext[k], Cs[k], z);
            z = fmaf(ext[24], dvs, z);
            z = fmaf(ext[25], rad, z);
            z = fmaf(ext[26], tmx, z);
            z = fmaf(ext[27], tmn, z);
            z = fmaf(ext[28], Ncum, z);

            float pm = (l < 24) ? z : -1e30f;
#pragma unroll
            for (int o = 1; o < 32; o <<= 1) pm = fmaxf(pm, __shfl_xor(pm, o, 32));
            float pe = (l < 24) ? __expf(z - pm) : 0.f;
            float ps = pe;
#pragma unroll
            for (int o = 1; o < 32; o <<= 1) ps += __shfl_xor(ps, o, 32);
            const float conz = __shfl(z, 24 + (l & 31), 64);
            const float asmz = __shfl(z, 48, 64);
            if (l < 24) {
                const float part = __fdividef(pe, ps);
                const float cmv = cbuf[l];
                cmb[l] = (cmv + sigm(asmz) * cpot * part) * (1.f - sigm(conz));
            }
        }
        __syncthreads();   // B1: zb + cmid ready

        // ---- row softmax: 2 lanes/row; wave0=kind0, wave1=kind1; P stored col-major ----
        {
            const bool act = (l < 48) && ((wv == 0) ? do1 : doCv);
            if (act) {
                const int r = l >> 1, h = l & 1;
                const float* zs = (wv == 0) ? zb1 : zb2;
                float* pd = (wv == 0) ? pb1 : pb2;
                float z[12];
#pragma unroll
                for (int i = 0; i < 12; ++i) z[i] = zs[r * 25 + h * 12 + i];
                float m = z[0];
#pragma unroll
                for (int i = 1; i < 12; ++i) m = fmaxf(m, z[i]);
                m = fmaxf(m, __shfl_xor(m, 1));
                float s = 0.f;
#pragma unroll
                for (int i = 0; i < 12; ++i) { z[i] = __expf(z[i] - m); s += z[i]; }
                s += __shfl_xor(s, 1);
                const float mlt = (wv == 0) ? cmb[r] : cbuf[r];
                const float f = __fdividef(mlt, s);
#pragma unroll
                for (int i = 0; i < 12; ++i) pd[(h * 12 + i) * 28 + r] = z[i] * f;
            }
        }
        __syncthreads();   // B2: scaled P (col-major) ready

        // ---- colsum (2 lanes/col, b128) + outputs + folded all_day ----
        {
            const bool a0 = (wv == 0) && (l < 48) && do1;
            const bool a1 = (wv == 1) && (l < 48) && doCv;
            const int c = l >> 1, h = l & 1;
            float s = 0.f;
            if (a0 || a1) {
                const float* psrc = (wv == 0) ? pb1 : pb2;
                const float4* p4 = (const float4*)&psrc[c * 28 + h * 12];
#pragma unroll
                for (int i = 0; i < 3; ++i) {
                    const float4 v = p4[i];
                    s += (v.x + v.y) + (v.z + v.w);
                }
                s += __shfl_xor(s, 1);
            }
            if (a1 && h == 0) Cconv[((size_t)b * NS_ + (u - 1)) * CD_ + c] = s;
            if (a0 && h == 0) {
                cbuf[c] = s;
                Ccell[((size_t)b * NS_ + u) * CD_ + c] = s;
            }
            if (wv == 0 && do1) {
                const float cv = even ? s : 0.f;     // lane 2c holds C_new[c]
                const float pv = fabsf(cv * c2);
                const float yv = fabsf(cv * gy);
                float a16 = cv, p16 = pv, y16 = yv;
#pragma unroll
                for (int o = 1; o < 16; o <<= 1) {
                    a16 += __shfl_xor(a16, o, 16);
                    p16 += __shfl_xor(p16, o, 16);
                    y16 += __shfl_xor(y16, o, 16);
                }
                const float pai = rl(p16, 0) + rl(p16, 16) + rl(p16, 32);
                const float lea = rl(a16, 0)  * (1.f / 0.419f);
                const float ste = rl(a16, 16) * (1.f / 0.431f);
                const float gra = rl(a16, 32) * (1.f / 0.487f);
                const float yie = rl(y16, 32) * (1.f / 0.487f);
                const float agb = lea + ste + gra;
                const float dvsn = orow[(u + 1) * 7];
                if (l < 7) {
                    float val = dvsn;
                    val = (l == 1) ? pai : val;
                    val = (l == 2) ? lea : val;
                    val = (l == 3) ? ste : val;
                    val = (l == 4) ? gra : val;
                    val = (l == 5) ? agb : val;
                    val = (l == 6) ? yie : val;
                    allday[((size_t)b * T_ + (u + 1)) * 7 + l] = val;
                }
            }
        }
        __syncthreads();   // B3: C(t+1) visible
        radp = rad;
    }
}

extern "C" void kernel_launch(void* const* d_in, const int* in_sizes, int n_in,
                              void* d_out, int out_size, void* d_ws, size_t ws_size,
                              hipStream_t stream) {
    const float* X   = (const float*)d_in[0];
    const float* ORY = (const float*)d_in[1];
    const float* Wr  = (const float*)d_in[2];
    const float* br  = (const float*)d_in[3];
    const float* Wp  = (const float*)d_in[4];
    const float* bp  = (const float*)d_in[5];
    const float* Wc  = (const float*)d_in[6];
    const float* bc  = (const float*)d_in[7];
    const float* Wa  = (const float*)d_in[8];
    const float* ba  = (const float*)d_in[9];
    const float* c2a = (const float*)d_in[10];
    const float* g2y = (const float*)d_in[11];

    float* allday = (float*)d_out;
    float* Ccell  = allday + (size_t)B_ * T_ * 7;
    float* Cconv  = Ccell + (size_t)B_ * NS_ * CD_;

    float* Wpk = (float*)d_ws;            // 576*32 floats
    float* Apk = Wpk + 576 * 32;          // 49*32 floats

    hipLaunchKernelGGL(mclstm_pack, dim3(10), dim3(64), 0, stream,
                       Wr, br, Wp, bp, Wc, bc, Wa, ba, Wpk, Apk);
    hipLaunchKernelGGL(mclstm_main, dim3(B_), dim3(128), 0, stream,
                       X, ORY, Wpk, Apk, c2a, g2y, allday, Ccell, Cconv);
}